// Round 2
// baseline (161.032 us; speedup 1.0000x reference)
//
#include <hip/hip_runtime.h>
#include <math.h>

#define HH 512
#define WW 512
#define NB 8
#define NC 3
#define HW (HH*WW)

#define TX 64
#define TY 32
#define HB_ROWS 42   // global rows ty0-5 .. ty0+36
#define HB_COLS 66   // global cols tx0-1 .. tx0+64
#define BL_ROWS 34   // global rows ty0-1 .. ty0+32
#define BL_COLS 66
#define HB_ITEMS (HB_ROWS*HB_COLS)   // 2772
#define BL_ITEMS (BL_ROWS*BL_COLS)   // 2244

// K1: per-batch 64x32 tile. h-gauss (9 tap, zero-pad, f64) straight from global img,
// v-gauss from LDS, sobel on blur (blur zero-padded at image borders), summed over 3
// channels. GM = sum_c sqrt(gx^2+gy^2); sector kp via slope comparisons (== rint-based
// atan2 sectorization, ties round-half-even consistent).
__global__ __launch_bounds__(256) void canny_gm_kernel(
    const float* __restrict__ img, const float* __restrict__ gwin,
    double* __restrict__ GM, unsigned char* __restrict__ KP)
{
    __shared__ double shb[HB_ROWS][HB_COLS];   // 22176 B
    __shared__ double sbl[BL_ROWS][BL_COLS];   // 17952 B  (total 40128 <= 40960)

    const int tilesX = WW / TX;                 // 8
    const int tx0 = (blockIdx.x % tilesX) * TX;
    const int ty0 = (blockIdx.x / tilesX) * TY;
    const int b = blockIdx.y;
    const int t = threadIdx.x;

    double g[9];
#pragma unroll
    for (int k = 0; k < 9; ++k) g[k] = (double)gwin[k];

    const int jj = t & 63;   // output col within tile
    const int w  = t >> 6;   // 0..3

    double mag[8], sgx[8], sgy[8];
#pragma unroll
    for (int p = 0; p < 8; ++p) { mag[p] = 0.0; sgx[p] = 0.0; sgy[p] = 0.0; }

    const bool safeX = (tx0 >= 8) && (tx0 + TX + 8 <= WW);

    const int hr0 = t / HB_COLS, hc0 = t % HB_COLS;  // one div/mod, hoisted

    for (int c = 0; c < NC; ++c) {
        const float* ip = img + ((size_t)b * NC + c) * HW;

        // ---- H phase: shb[r][cc] = sum_k g[k]*img[ty0-5+r][tx0-5+cc+k] (zero-pad)
        {
            int r = hr0, cc = hc0, idx = t;
#pragma unroll 1
            for (int it = 0; it < 11; ++it) {
                if (idx < HB_ITEMS) {
                    int gr = ty0 - 5 + r;
                    double acc = 0.0;
                    if ((unsigned)gr < (unsigned)HH) {
                        if (safeX) {
                            const float* rp = ip + (size_t)gr * WW + (tx0 - 5 + cc);
#pragma unroll
                            for (int k = 0; k < 9; ++k) acc += g[k] * (double)rp[k];
                        } else {
                            int gcb = tx0 - 5 + cc;
                            const float* rowp = ip + (size_t)gr * WW;
#pragma unroll
                            for (int k = 0; k < 9; ++k) {
                                int gc = gcb + k;
                                float v = ((unsigned)gc < (unsigned)WW) ? rowp[gc] : 0.0f;
                                acc += g[k] * (double)v;
                            }
                        }
                    }
                    shb[r][cc] = acc;
                }
                idx += 256; r += 3; cc += 58;            // 256 = 3*66 + 58
                if (cc >= HB_COLS) { cc -= HB_COLS; r += 1; }
            }
        }
        __syncthreads();

        // ---- V phase: sbl[r][cc] = sum_k g[k]*shb[r+k][cc]
        {
            int r = hr0, cc = hc0, idx = t;              // same 66-col mapping
#pragma unroll 1
            for (int it = 0; it < 9; ++it) {
                if (idx < BL_ITEMS) {
                    double acc = 0.0;
#pragma unroll
                    for (int k = 0; k < 9; ++k) acc += g[k] * shb[r + k][cc];
                    sbl[r][cc] = acc;
                }
                idx += 256; r += 3; cc += 58;
                if (cc >= BL_COLS) { cc -= BL_COLS; r += 1; }
            }
        }
        __syncthreads();

        // ---- S phase: sobel on blur with zero-pad masks at image borders
#pragma unroll
        for (int p = 0; p < 8; ++p) {
            int i = w + 4 * p;                 // 0..31
            int gi = ty0 + i, gj = tx0 + jj;
            bool up = (gi >= 1), dn = (gi <= HH - 2), lf = (gj >= 1), rt = (gj <= WW - 2);
            // sbl local row r <-> global ty0-1+r ; local col c <-> global tx0-1+c
            double tl = (up && lf) ? sbl[i][jj]     : 0.0;
            double tc = (up)       ? sbl[i][jj+1]   : 0.0;
            double tr = (up && rt) ? sbl[i][jj+2]   : 0.0;
            double ml = (lf)       ? sbl[i+1][jj]   : 0.0;
            double mr = (rt)       ? sbl[i+1][jj+2] : 0.0;
            double bl = (dn && lf) ? sbl[i+2][jj]   : 0.0;
            double bc = (dn)       ? sbl[i+2][jj+1] : 0.0;
            double br = (dn && rt) ? sbl[i+2][jj+2] : 0.0;
            double gx = (tl - tr) + 2.0*(ml - mr) + (bl - br);
            double gy = (tl + 2.0*tc + tr) - (bl + 2.0*bc + br);
            mag[p] += sqrt(gx*gx + gy*gy);
            sgx[p] += gx; sgy[p] += gy;
        }
        __syncthreads();
    }

    // ---- output: GM + sector (replaces rint(atan2-based ori/45)&7; ties half-even)
    const double t225 = 0.41421356237309503;   // tan(22.5 deg)
    const double t675 = 2.414213562373095;     // tan(67.5 deg)
#pragma unroll
    for (int p = 0; p < 8; ++p) {
        int i = w + 4 * p;
        size_t o = (size_t)b * HW + (size_t)(ty0 + i) * WW + (tx0 + jj);
        GM[o] = mag[p];
        double sx = sgx[p], sy = sgy[p];
        double ax = fabs(sx), ay = fabs(sy);
        int kp;
        if (ay <= ax * t225)      kp = (sx >= 0.0) ? 4 : 0;
        else if (ay >= ax * t675) kp = (sy > 0.0) ? 6 : 2;
        else if (sx > 0.0)        kp = (sy > 0.0) ? 5 : 3;
        else                      kp = (sy > 0.0) ? 7 : 1;
        KP[o] = (unsigned char)kp;
    }
}

// K2: faithful replication of the flat gather (batch<->direction swap):
// pos(b,i,j) = GM[kp,i,j] - GM[kp, i+dr(b), j+dc(b)] (0 if neighbor OOB)
// neg uses kn = (kp+4)&7. thin = min(pos,neg)>0 ? GM[b,i,j] : 0.
// code bit0: thin > 0.3 ; bit1: 0.1 <= thin <= 0.3
__global__ __launch_bounds__(256) void canny_thin_kernel(
    const double* __restrict__ GM, const unsigned char* __restrict__ KP,
    unsigned char* __restrict__ CODE)
{
    int idx = blockIdx.x * blockDim.x + threadIdx.x;
    if (idx >= NB * HW) return;
    int j = idx & (WW - 1);
    int i = (idx >> 9) & (HH - 1);
    int b = idx >> 18;

    // dr+1 per b (digits b7..b0): 0,0,0,1,2,2,2,1 ; dc+1: 2,1,0,0,0,1,2,2
    int dr = (int)((0x00012221u >> (b * 4)) & 15u) - 1;
    int dc = (int)((0x21000122u >> (b * 4)) & 15u) - 1;

    int kp = KP[idx];
    int kn = (kp + 4) & 7;
    int ni = i + dr, nj = j + dc;
    bool nin = ((unsigned)ni < (unsigned)HH) && ((unsigned)nj < (unsigned)WW);
    size_t p0 = (size_t)i * WW + j;
    size_t pn = (size_t)ni * WW + nj;

    double gmp  = GM[(size_t)kp * HW + p0];
    double gmn  = GM[(size_t)kn * HW + p0];
    double gmpn = nin ? GM[(size_t)kp * HW + pn] : 0.0;
    double gmnn = nin ? GM[(size_t)kn * HW + pn] : 0.0;

    double pos = gmp - gmpn;
    double neg = gmn - gmnn;
    double thin = (fmin(pos, neg) > 0.0) ? GM[idx] : 0.0;

    unsigned char code = 0;
    if (thin > 0.3) code |= 1;
    if (thin >= 0.1 && thin <= 0.3) code |= 2;
    CODE[idx] = code;
}

// K3: out = !border && (higher || (middle && any 8-neighbor higher))
__global__ __launch_bounds__(256) void canny_out_kernel(
    const unsigned char* __restrict__ CODE, float* __restrict__ out)
{
    int idx = blockIdx.x * blockDim.x + threadIdx.x;
    if (idx >= NB * HW) return;
    int j = idx & (WW - 1);
    int i = (idx >> 9) & (HH - 1);
    int b = idx >> 18;

    float r = 0.0f;
    if (i > 0 && i < HH - 1 && j > 0 && j < WW - 1) {
        unsigned char c = CODE[idx];
        if (c & 1) {
            r = 1.0f;
        } else if (c & 2) {
            const unsigned char* base = CODE + (size_t)b * HW;
            int any = 0;
            any |= base[(size_t)(i-1)*WW + (j-1)] & 1;
            any |= base[(size_t)(i-1)*WW + (j  )] & 1;
            any |= base[(size_t)(i-1)*WW + (j+1)] & 1;
            any |= base[(size_t)(i  )*WW + (j-1)] & 1;
            any |= base[(size_t)(i  )*WW + (j+1)] & 1;
            any |= base[(size_t)(i+1)*WW + (j-1)] & 1;
            any |= base[(size_t)(i+1)*WW + (j  )] & 1;
            any |= base[(size_t)(i+1)*WW + (j+1)] & 1;
            if (any) r = 1.0f;
        }
    }
    out[idx] = r;
}

extern "C" void kernel_launch(void* const* d_in, const int* in_sizes, int n_in,
                              void* d_out, int out_size, void* d_ws, size_t ws_size,
                              hipStream_t stream) {
    const float* img  = (const float*)d_in[0];
    const float* gwin = (const float*)d_in[1];

    double* GM = (double*)d_ws;
    unsigned char* KP = (unsigned char*)d_ws + (size_t)NB * HW * sizeof(double);
    unsigned char* CODE = KP + (size_t)NB * HW;
    float* out = (float*)d_out;

    dim3 g1((WW / TX) * (HH / TY), NB);   // (128, 8) = 1024 blocks
    canny_gm_kernel<<<g1, 256, 0, stream>>>(img, gwin, GM, KP);

    int nblk = (NB * HW) / 256;
    canny_thin_kernel<<<nblk, 256, 0, stream>>>(GM, KP, CODE);
    canny_out_kernel<<<nblk, 256, 0, stream>>>(CODE, out);
}

// Round 3
// 85.169 us; speedup vs baseline: 1.8907x; 1.8907x over previous
//
#include <hip/hip_runtime.h>
#include <math.h>

#define HH 512
#define WW 512
#define NB 8
#define NC 3
#define HW (HH*WW)

#define TS 32               // tile 32x32
#define IM_R 42             // img tile rows   (ty0-5 .. ty0+36)
#define IM_C 42             // img tile cols   (tx0-5 .. tx0+36)
#define HB_R 42             // h-blur rows     (ty0-5 .. ty0+36)
#define HB_C 34             // h-blur cols     (tx0-1 .. tx0+32)
#define HB_S 35             // padded stride
#define BL_R 34             // blur rows       (ty0-1 .. ty0+32)
#define BL_C 34             // blur cols       (tx0-1 .. tx0+32)
#define BL_S 35             // padded stride
#define IM_ITEMS (IM_R*IM_C)     // 1764
#define HB_ITEMS (HB_R*HB_C)     // 1428
#define BL_ITEMS (BL_R*BL_C)     // 1156

// K1: per-batch 32x32 tile. img staged in LDS (f32), h-gauss -> LDS f64,
// v-gauss -> LDS f64 (aliased over the img stage), sobel on blur (blur
// zero-padded at image borders), summed over 3 channels.
// GM = sum_c sqrt(gx^2+gy^2) (f64); sector kp via slope comparisons
// (== rint((atan2*180/pi+180)/45)&7 with half-even ties, verified).
__global__ __launch_bounds__(256) void canny_gm_kernel(
    const float* __restrict__ img, const float* __restrict__ gwin,
    double* __restrict__ GM, unsigned char* __restrict__ KP)
{
    __shared__ double shb[HB_R][HB_S];                         // 11760 B
    __shared__ __align__(16) unsigned char upool[BL_R*BL_S*8]; //  9520 B (>= 7056 img stage)
    float  (*simg)[IM_C] = (float  (*)[IM_C])upool;
    double (*sbl )[BL_S] = (double (*)[BL_S])upool;

    const int tilesX = WW / TS;                 // 16
    const int tx0 = (blockIdx.x % tilesX) * TS;
    const int ty0 = (blockIdx.x / tilesX) * TS;
    const int b = blockIdx.y;
    const int t = threadIdx.x;

    double g[9];
#pragma unroll
    for (int k = 0; k < 9; ++k) g[k] = (double)gwin[k];

    // hoisted index starts (channel-invariant)
    const int lr0 = t / IM_C, lc0 = t % IM_C;   // width-42 walk
    const int hr0 = t / HB_C, hc0 = t % HB_C;   // width-34 walk

    // output pixel mapping: 4 px/thread
    const int jj = t & 31;          // col in tile
    const int ii0 = t >> 5;         // row base (rows ii0, ii0+8, +16, +24)

    double mag[4], sgx[4], sgy[4];
#pragma unroll
    for (int p = 0; p < 4; ++p) { mag[p] = 0.0; sgx[p] = 0.0; sgy[p] = 0.0; }

    for (int c = 0; c < NC; ++c) {
        const float* ip = img + ((size_t)b * NC + c) * HW;

        // ---- stage img tile (halo 5, zero-pad) : 1764 items, 7 strided steps
        {
            int r = lr0, cc = lc0, idx = t;
#pragma unroll
            for (int it = 0; it < 7; ++it) {
                if (idx < IM_ITEMS) {
                    int gr = ty0 - 5 + r, gc = tx0 - 5 + cc;
                    float v = 0.0f;
                    if ((unsigned)gr < (unsigned)HH && (unsigned)gc < (unsigned)WW)
                        v = ip[(size_t)gr * WW + gc];
                    simg[r][cc] = v;
                }
                idx += 256; r += 6; cc += 4;          // 256 = 6*42 + 4
                if (cc >= IM_C) { cc -= IM_C; ++r; }
            }
        }
        __syncthreads();

        // ---- H: shb[r][cc] = sum_k g[k]*simg[r][cc+k] : 1428 items, 6 steps
        {
            int r = hr0, cc = hc0, idx = t;
#pragma unroll
            for (int it = 0; it < 6; ++it) {
                if (idx < HB_ITEMS) {
                    double acc = 0.0;
#pragma unroll
                    for (int k = 0; k < 9; ++k) acc = fma(g[k], (double)simg[r][cc + k], acc);
                    shb[r][cc] = acc;
                }
                idx += 256; r += 7; cc += 18;         // 256 = 7*34 + 18
                if (cc >= HB_C) { cc -= HB_C; ++r; }
            }
        }
        __syncthreads();

        // ---- V: sbl[r][cc] = sum_k g[k]*shb[r+k][cc] : 1156 items, 5 steps
        //      (overwrites simg region -- simg fully consumed above)
        {
            int r = hr0, cc = hc0, idx = t;
#pragma unroll
            for (int it = 0; it < 5; ++it) {
                if (idx < BL_ITEMS) {
                    double acc = 0.0;
#pragma unroll
                    for (int k = 0; k < 9; ++k) acc = fma(g[k], shb[r + k][cc], acc);
                    sbl[r][cc] = acc;
                }
                idx += 256; r += 7; cc += 18;
                if (cc >= BL_C) { cc -= BL_C; ++r; }
            }
        }
        __syncthreads();

        // ---- Sobel on blur (zero-pad of blur at image borders), accumulate
        {
            const int gj = tx0 + jj;
            const bool lf = (gj >= 1), rt = (gj <= WW - 2);
#pragma unroll
            for (int p = 0; p < 4; ++p) {
                int i = ii0 + 8 * p;                 // 0..31
                int gi = ty0 + i;
                bool up = (gi >= 1), dn = (gi <= HH - 2);
                // sbl local row r <-> global ty0-1+r ; local col c <-> global tx0-1+c
                double tl = (up && lf) ? sbl[i][jj]     : 0.0;
                double tc = (up)       ? sbl[i][jj+1]   : 0.0;
                double tr = (up && rt) ? sbl[i][jj+2]   : 0.0;
                double ml = (lf)       ? sbl[i+1][jj]   : 0.0;
                double mr = (rt)       ? sbl[i+1][jj+2] : 0.0;
                double bl = (dn && lf) ? sbl[i+2][jj]   : 0.0;
                double bc = (dn)       ? sbl[i+2][jj+1] : 0.0;
                double br = (dn && rt) ? sbl[i+2][jj+2] : 0.0;
                double gx = (tl - tr) + 2.0*(ml - mr) + (bl - br);
                double gy = (tl + 2.0*tc + tr) - (bl + 2.0*bc + br);
                mag[p] += sqrt(gx*gx + gy*gy);
                sgx[p] += gx; sgy[p] += gy;
            }
        }
        __syncthreads();   // protect LDS before next channel's stage
    }

    // ---- write GM + sector
    const double t225 = 0.41421356237309503;   // tan(22.5 deg)
    const double t675 = 2.414213562373095;     // tan(67.5 deg)
#pragma unroll
    for (int p = 0; p < 4; ++p) {
        int i = ii0 + 8 * p;
        size_t o = (size_t)b * HW + (size_t)(ty0 + i) * WW + (tx0 + jj);
        GM[o] = mag[p];
        double sx = sgx[p], sy = sgy[p];
        double ax = fabs(sx), ay = fabs(sy);
        int kp;
        if (ay <= ax * t225)      kp = (sx >= 0.0) ? 4 : 0;
        else if (ay >= ax * t675) kp = (sy > 0.0) ? 6 : 2;
        else if (sx > 0.0)        kp = (sy > 0.0) ? 5 : 3;
        else                      kp = (sy > 0.0) ? 7 : 1;
        KP[o] = (unsigned char)kp;
    }
}

// K2: faithful replication of the flat gather (batch<->direction swap):
// pos(b,i,j) = GM[kp,i,j] - GM[kp, i+dr(b), j+dc(b)] (0 if neighbor OOB)
// neg uses kn = (kp+4)&7. thin = min(pos,neg)>0 ? GM[b,i,j] : 0.
// code bit0: thin > 0.3 ; bit1: 0.1 <= thin <= 0.3
__global__ __launch_bounds__(256) void canny_thin_kernel(
    const double* __restrict__ GM, const unsigned char* __restrict__ KP,
    unsigned char* __restrict__ CODE)
{
    int idx = blockIdx.x * blockDim.x + threadIdx.x;
    if (idx >= NB * HW) return;
    int j = idx & (WW - 1);
    int i = (idx >> 9) & (HH - 1);
    int b = idx >> 18;

    // dr+1 per b (digits b7..b0): 0,0,0,1,2,2,2,1 ; dc+1: 2,1,0,0,0,1,2,2
    int dr = (int)((0x00012221u >> (b * 4)) & 15u) - 1;
    int dc = (int)((0x21000122u >> (b * 4)) & 15u) - 1;

    int kp = KP[idx];
    int kn = (kp + 4) & 7;
    int ni = i + dr, nj = j + dc;
    bool nin = ((unsigned)ni < (unsigned)HH) && ((unsigned)nj < (unsigned)WW);
    size_t p0 = (size_t)i * WW + j;
    size_t pn = (size_t)ni * WW + nj;

    double gmp  = GM[(size_t)kp * HW + p0];
    double gmn  = GM[(size_t)kn * HW + p0];
    double gmpn = nin ? GM[(size_t)kp * HW + pn] : 0.0;
    double gmnn = nin ? GM[(size_t)kn * HW + pn] : 0.0;

    double pos = gmp - gmpn;
    double neg = gmn - gmnn;
    double thin = (fmin(pos, neg) > 0.0) ? GM[idx] : 0.0;

    unsigned char code = 0;
    if (thin > 0.3) code |= 1;
    if (thin >= 0.1 && thin <= 0.3) code |= 2;
    CODE[idx] = code;
}

// K3: out = !border && (higher || (middle && any 8-neighbor higher))
__global__ __launch_bounds__(256) void canny_out_kernel(
    const unsigned char* __restrict__ CODE, float* __restrict__ out)
{
    int idx = blockIdx.x * blockDim.x + threadIdx.x;
    if (idx >= NB * HW) return;
    int j = idx & (WW - 1);
    int i = (idx >> 9) & (HH - 1);
    int b = idx >> 18;

    float r = 0.0f;
    if (i > 0 && i < HH - 1 && j > 0 && j < WW - 1) {
        unsigned char c = CODE[idx];
        if (c & 1) {
            r = 1.0f;
        } else if (c & 2) {
            const unsigned char* base = CODE + (size_t)b * HW;
            int any = 0;
            any |= base[(size_t)(i-1)*WW + (j-1)] & 1;
            any |= base[(size_t)(i-1)*WW + (j  )] & 1;
            any |= base[(size_t)(i-1)*WW + (j+1)] & 1;
            any |= base[(size_t)(i  )*WW + (j-1)] & 1;
            any |= base[(size_t)(i  )*WW + (j+1)] & 1;
            any |= base[(size_t)(i+1)*WW + (j-1)] & 1;
            any |= base[(size_t)(i+1)*WW + (j  )] & 1;
            any |= base[(size_t)(i+1)*WW + (j+1)] & 1;
            if (any) r = 1.0f;
        }
    }
    out[idx] = r;
}

extern "C" void kernel_launch(void* const* d_in, const int* in_sizes, int n_in,
                              void* d_out, int out_size, void* d_ws, size_t ws_size,
                              hipStream_t stream) {
    const float* img  = (const float*)d_in[0];
    const float* gwin = (const float*)d_in[1];

    double* GM = (double*)d_ws;
    unsigned char* KP = (unsigned char*)d_ws + (size_t)NB * HW * sizeof(double);
    unsigned char* CODE = KP + (size_t)NB * HW;
    float* out = (float*)d_out;

    dim3 g1((WW / TS) * (HH / TS), NB);   // (256, 8) = 2048 blocks
    canny_gm_kernel<<<g1, 256, 0, stream>>>(img, gwin, GM, KP);

    int nblk = (NB * HW) / 256;
    canny_thin_kernel<<<nblk, 256, 0, stream>>>(GM, KP, CODE);
    canny_out_kernel<<<nblk, 256, 0, stream>>>(CODE, out);
}

// Round 4
// 77.255 us; speedup vs baseline: 2.0844x; 1.1024x over previous
//
#include <hip/hip_runtime.h>
#include <math.h>

#define HH 512
#define WW 512
#define NB 8
#define NC 3
#define HW (HH*WW)

#define RSTRIP 16                         // output rows per wave
#define CSTRIP 62                         // output cols per wave (64 blur cols, 2 halo)
#define NROWS (HH/RSTRIP)                 // 32
#define NCOLS ((WW + CSTRIP - 1)/CSTRIP)  // 9

// K1: register row-streaming separable conv. One wave per (62-col x 16-row) strip.
// Per img row r: h-blur (9 masked global f32 loads -> f64 fma) into a 9-deep
// register ring; v-blur (9 f64 fma over ring) into a 3-deep register ring;
// sobel on v-blur via __shfl neighbors. Tap masks / fma order bit-identical to
// the r3 LDS kernel (absmax 0.0 proven). No LDS, no barriers.
__global__ __launch_bounds__(64) void canny_gm_kernel(
    const float* __restrict__ img, const float* __restrict__ gwin,
    double* __restrict__ GM, unsigned char* __restrict__ KP)
{
    const int lane = threadIdx.x;              // 0..63
    const int cs   = blockIdx.x % NCOLS;
    const int rs   = blockIdx.x / NCOLS;
    const int b    = blockIdx.y;

    const int R0 = rs * RSTRIP;
    const int c0 = cs * CSTRIP - 1;            // blur col of lane 0
    const int cl = c0 + lane;                  // this lane's blur column

    double g[9];
#pragma unroll
    for (int k = 0; k < 9; ++k) g[k] = (double)gwin[k];

    // 9-tap column window: clamped indices + masks (shared by all channels/rows)
    int cidx[9]; bool cmask[9];
#pragma unroll
    for (int k = 0; k < 9; ++k) {
        int cc = cl - 4 + k;
        cmask[k] = ((unsigned)cc < (unsigned)WW);
        int cc2 = cc < 0 ? 0 : cc;
        cidx[k] = cc2 > (WW - 1) ? (WW - 1) : cc2;
    }
    const bool lane_out = (lane >= 1) && (lane <= CSTRIP) && (cl < WW);
    const bool cml = ((unsigned)(cl - 1) < (unsigned)WW);   // col cl-1 valid
    const bool cmr = ((unsigned)(cl + 1) < (unsigned)WW);   // col cl+1 valid

    const float* ip0 = img + ((size_t)b * NC + 0) * HW;
    const float* ip1 = img + ((size_t)b * NC + 1) * HW;
    const float* ip2 = img + ((size_t)b * NC + 2) * HW;

    double hb[3][9];   // h-blur ring: row r lives in slot ph (phase of chunk)
    double vb[3][3];   // v-blur ring: row r-4 in slot (ph+2)%3
#pragma unroll
    for (int c = 0; c < 3; ++c) {
#pragma unroll
        for (int k = 0; k < 9; ++k) hb[c][k] = 0.0;
#pragma unroll
        for (int k = 0; k < 3; ++k) vb[c][k] = 0.0;
    }

    const double t225 = 0.41421356237309503;   // tan(22.5 deg)
    const double t675 = 2.414213562373095;     // tan(67.5 deg)
    const int rEnd = R0 + RSTRIP + 4;          // last img row needed

#pragma unroll 1
    for (int chunk = 0; chunk < 3; ++chunk) {
        const int rbase = R0 - 5 + 9 * chunk;
#pragma unroll
        for (int ph = 0; ph < 9; ++ph) {
            const int r = rbase + ph;
            if (r > rEnd) continue;                       // wave-uniform

            // ---- h-blur of img row r -> hb[c][ph] (zero row-pad outside image)
            if ((unsigned)r < (unsigned)HH) {
                const size_t ro = (size_t)r * WW;
                float v0[9], v1[9], v2[9];
#pragma unroll
                for (int k = 0; k < 9; ++k) {
                    v0[k] = ip0[ro + cidx[k]];
                    v1[k] = ip1[ro + cidx[k]];
                    v2[k] = ip2[ro + cidx[k]];
                }
                double a0 = 0.0, a1 = 0.0, a2 = 0.0;
#pragma unroll
                for (int k = 0; k < 9; ++k) {
                    a0 = fma(g[k], (double)(cmask[k] ? v0[k] : 0.0f), a0);
                    a1 = fma(g[k], (double)(cmask[k] ? v1[k] : 0.0f), a1);
                    a2 = fma(g[k], (double)(cmask[k] ? v2[k] : 0.0f), a2);
                }
                hb[0][ph] = a0; hb[1][ph] = a1; hb[2][ph] = a2;
            } else {
                hb[0][ph] = 0.0; hb[1][ph] = 0.0; hb[2][ph] = 0.0;
            }

            // ---- v-blur row rv = r-4 -> vb[c][(ph+2)%3]
            // tap row rv-4+k = r-8+k lives in slot (ph+1+k)%9
            if (r - 4 >= R0 - 1) {
#pragma unroll
                for (int c = 0; c < 3; ++c) {
                    double acc = 0.0;
#pragma unroll
                    for (int k = 0; k < 9; ++k)
                        acc = fma(g[k], hb[c][(ph + 1 + k) % 9], acc);
                    vb[c][(ph + 2) % 3] = acc;
                }
            }

            // ---- sobel + GM/sector at row ri = r-5
            const int ri = r - 5;
            if (ri >= R0) {
                const bool up = (ri >= 1), dn = (ri <= HH - 2);
                double mag = 0.0, sgx = 0.0, sgy = 0.0;
#pragma unroll
                for (int c = 0; c < 3; ++c) {
                    double top = up ? vb[c][ph % 3]       : 0.0;  // row ri-1 (row-masked)
                    double mid =      vb[c][(ph + 1) % 3];        // row ri
                    double bot = dn ? vb[c][(ph + 2) % 3] : 0.0;  // row ri+1 (row-masked)
                    double tl_ = __shfl_up(top, 1), tr_ = __shfl_down(top, 1);
                    double ml_ = __shfl_up(mid, 1), mr_ = __shfl_down(mid, 1);
                    double bl_ = __shfl_up(bot, 1), br_ = __shfl_down(bot, 1);
                    double tl = cml ? tl_ : 0.0, tr = cmr ? tr_ : 0.0;
                    double ml = cml ? ml_ : 0.0, mr = cmr ? mr_ : 0.0;
                    double bl = cml ? bl_ : 0.0, br = cmr ? br_ : 0.0;
                    double tc = top, bc = bot;
                    double gx = (tl - tr) + 2.0*(ml - mr) + (bl - br);
                    double gy = (tl + 2.0*tc + tr) - (bl + 2.0*bc + br);
                    mag += sqrt(gx*gx + gy*gy);
                    sgx += gx; sgy += gy;
                }
                if (lane_out) {
                    size_t o = (size_t)b * HW + (size_t)ri * WW + cl;
                    GM[o] = mag;
                    double ax = fabs(sgx), ay = fabs(sgy);
                    int kp;
                    if (ay <= ax * t225)      kp = (sgx >= 0.0) ? 4 : 0;
                    else if (ay >= ax * t675) kp = (sgy > 0.0) ? 6 : 2;
                    else if (sgx > 0.0)       kp = (sgy > 0.0) ? 5 : 3;
                    else                      kp = (sgy > 0.0) ? 7 : 1;
                    KP[o] = (unsigned char)kp;
                }
            }
        }
    }
}

// K2: faithful replication of the flat gather (batch<->direction swap):
// pos(b,i,j) = GM[kp,i,j] - GM[kp, i+dr(b), j+dc(b)] (0 if neighbor OOB)
// neg uses kn = (kp+4)&7. thin = min(pos,neg)>0 ? GM[b,i,j] : 0.
// code bit0: thin > 0.3 ; bit1: 0.1 <= thin <= 0.3
__global__ __launch_bounds__(256) void canny_thin_kernel(
    const double* __restrict__ GM, const unsigned char* __restrict__ KP,
    unsigned char* __restrict__ CODE)
{
    int idx = blockIdx.x * blockDim.x + threadIdx.x;
    if (idx >= NB * HW) return;
    int j = idx & (WW - 1);
    int i = (idx >> 9) & (HH - 1);
    int b = idx >> 18;

    // dr+1 per b (digits b7..b0): 0,0,0,1,2,2,2,1 ; dc+1: 2,1,0,0,0,1,2,2
    int dr = (int)((0x00012221u >> (b * 4)) & 15u) - 1;
    int dc = (int)((0x21000122u >> (b * 4)) & 15u) - 1;

    int kp = KP[idx];
    int kn = (kp + 4) & 7;
    int ni = i + dr, nj = j + dc;
    bool nin = ((unsigned)ni < (unsigned)HH) && ((unsigned)nj < (unsigned)WW);
    size_t p0 = (size_t)i * WW + j;
    size_t pn = (size_t)ni * WW + nj;

    double gmp  = GM[(size_t)kp * HW + p0];
    double gmn  = GM[(size_t)kn * HW + p0];
    double gmpn = nin ? GM[(size_t)kp * HW + pn] : 0.0;
    double gmnn = nin ? GM[(size_t)kn * HW + pn] : 0.0;

    double pos = gmp - gmpn;
    double neg = gmn - gmnn;
    double thin = (fmin(pos, neg) > 0.0) ? GM[idx] : 0.0;

    unsigned char code = 0;
    if (thin > 0.3) code |= 1;
    if (thin >= 0.1 && thin <= 0.3) code |= 2;
    CODE[idx] = code;
}

// K3: out = !border && (higher || (middle && any 8-neighbor higher))
__global__ __launch_bounds__(256) void canny_out_kernel(
    const unsigned char* __restrict__ CODE, float* __restrict__ out)
{
    int idx = blockIdx.x * blockDim.x + threadIdx.x;
    if (idx >= NB * HW) return;
    int j = idx & (WW - 1);
    int i = (idx >> 9) & (HH - 1);
    int b = idx >> 18;

    float r = 0.0f;
    if (i > 0 && i < HH - 1 && j > 0 && j < WW - 1) {
        unsigned char c = CODE[idx];
        if (c & 1) {
            r = 1.0f;
        } else if (c & 2) {
            const unsigned char* base = CODE + (size_t)b * HW;
            int any = 0;
            any |= base[(size_t)(i-1)*WW + (j-1)] & 1;
            any |= base[(size_t)(i-1)*WW + (j  )] & 1;
            any |= base[(size_t)(i-1)*WW + (j+1)] & 1;
            any |= base[(size_t)(i  )*WW + (j-1)] & 1;
            any |= base[(size_t)(i  )*WW + (j+1)] & 1;
            any |= base[(size_t)(i+1)*WW + (j-1)] & 1;
            any |= base[(size_t)(i+1)*WW + (j  )] & 1;
            any |= base[(size_t)(i+1)*WW + (j+1)] & 1;
            if (any) r = 1.0f;
        }
    }
    out[idx] = r;
}

extern "C" void kernel_launch(void* const* d_in, const int* in_sizes, int n_in,
                              void* d_out, int out_size, void* d_ws, size_t ws_size,
                              hipStream_t stream) {
    const float* img  = (const float*)d_in[0];
    const float* gwin = (const float*)d_in[1];

    double* GM = (double*)d_ws;
    unsigned char* KP = (unsigned char*)d_ws + (size_t)NB * HW * sizeof(double);
    unsigned char* CODE = KP + (size_t)NB * HW;
    float* out = (float*)d_out;

    dim3 g1(NCOLS * NROWS, NB);   // (288, 8) = 2304 one-wave blocks
    canny_gm_kernel<<<g1, 64, 0, stream>>>(img, gwin, GM, KP);

    int nblk = (NB * HW) / 256;
    canny_thin_kernel<<<nblk, 256, 0, stream>>>(GM, KP, CODE);
    canny_out_kernel<<<nblk, 256, 0, stream>>>(CODE, out);
}